// Round 4
// baseline (114.970 us; speedup 1.0000x reference)
//
#include <hip/hip_runtime.h>
#include <hip/hip_bf16.h>

// AttentionHead: out = softmax((q@Wq^T+bq) @ (k@Wk^T+bk)^T / 16) @ (v@Wv^T+bv)
// N=8192, DK=DV=256. f32 in/out, bf16 32x32x16 MFMA internally.
//
// ws layout:
//   [0,4M)    Qimg bf16 — Q in QK B-fragment image order (pre-scaled 1/16)
//   [4M,8M)   Kimg bf16 — K in QK A-fragment image order
//   [8M,12M)  Vimg bf16 — V in PV B-fragment image order
//   [12M,..)  Op  f32  [SPLIT][8192][256]
//   [..]      Ml  float2 [SPLIT][8192]
//
// Image layouts (per 32-row kv/q block = 8192 shorts = 16 KB):
//   Kimg/Qimg: idx(r,k) = (r>>5)*8192 + (k>>4)*512 + ((k>>3)&1)*256 + (r&31)*8 + (k&7)
//   Vimg:      idx(kv,dv)= (kv>>5)*8192 + (dv>>5)*1024 + ((kv>>4)&1)*512
//                          + ((kv>>3)&1)*256 + (dv&31)*8 + (kv&7)
// These make LDS staging (global_load_lds) and all ds_read_b128 lane-linear.

typedef __attribute__((ext_vector_type(8))) short short8;
typedef __attribute__((ext_vector_type(4))) short short4v;
typedef __attribute__((ext_vector_type(4))) float f32x4;
typedef __attribute__((ext_vector_type(4))) float float4v;
typedef __attribute__((ext_vector_type(16))) float f32x16;

#define MFMA16 __builtin_amdgcn_mfma_f32_16x16x32_bf16
#define MFMA32 __builtin_amdgcn_mfma_f32_32x32x16_bf16

namespace {
constexpr int kN = 8192;
constexpr int kD = 256;
constexpr int kKVB = 32;   // kv rows per flash iteration
}

__device__ __forceinline__ unsigned short f2bf(float x) {
  union { float f; unsigned u; } v; v.f = x;
  unsigned r = v.u + 0x7FFFu + ((v.u >> 16) & 1u);  // RNE
  return (unsigned short)(r >> 16);
}

__device__ __forceinline__ unsigned cvtpk_bf16(float lo, float hi) {
  unsigned d;
  asm("v_cvt_pk_bf16_f32 %0, %1, %2" : "=v"(d) : "v"(lo), "v"(hi));
  return d;
}

__device__ __forceinline__ void gll16(const short* g, short* lp) {
  __builtin_amdgcn_global_load_lds(
      (const __attribute__((address_space(1))) void*)g,
      (__attribute__((address_space(3))) void*)lp, 16, 0, 0);
}

// ---------------------------------------------------------------------------
// proj: Y = X @ W^T + b -> fragment-image layouts.
// grid (128, 3): block owns a 64-row n-strip (X staged ONCE), loops 4 ob
// chunks of 64 o. Modes 0/1 use swapped operands (D rows = o) so image
// stores are coalesced short4v; mode 2 keeps D rows = n (Vimg short4v).
// ---------------------------------------------------------------------------
__global__ __launch_bounds__(256, 2) void proj_kernel(
    const float* __restrict__ qx, const float* __restrict__ kx, const float* __restrict__ vx,
    const float* __restrict__ Wq, const float* __restrict__ bq,
    const float* __restrict__ Wk, const float* __restrict__ bk,
    const float* __restrict__ Wv, const float* __restrict__ bv,
    short* __restrict__ Qimg, short* __restrict__ Kimg, short* __restrict__ Vimg)
{
  const int mode = blockIdx.y;
  const float* X; const float* W; const float* B;
  if (mode == 0)      { X = qx; W = Wq; B = bq; }
  else if (mode == 1) { X = kx; W = Wk; B = bk; }
  else                { X = vx; W = Wv; B = bv; }

  const int nb = blockIdx.x * 64;

  __shared__ short XA[64][264];
  __shared__ short WB[64][264];

  const int t  = threadIdx.x;
  const int c4 = t & 63;       // float4 column
  const int r0 = t >> 6;       // 4 rows/pass

  // stage X strip once (f32 -> bf16)
#pragma unroll
  for (int p = 0; p < 16; ++p) {
    const int r = p * 4 + r0;
    float4v xv = *(const float4v*)(X + (size_t)(nb + r) * kD + c4 * 4);
    short4v xs;
#pragma unroll
    for (int j = 0; j < 4; ++j) xs[j] = (short)f2bf(xv[j]);
    *(short4v*)(&XA[r][c4 * 4]) = xs;
  }

  const int w  = t >> 6;
  const int l  = t & 63;
  const int lr = l & 15;
  const int g  = l >> 4;

  for (int obi = 0; obi < 4; ++obi) {
    __syncthreads();   // protect WB from previous chunk's readers (covers XA 1st time)
#pragma unroll
    for (int p = 0; p < 16; ++p) {
      const int r = p * 4 + r0;
      float4v wv = *(const float4v*)(W + (size_t)(obi * 64 + r) * kD + c4 * 4);
      short4v wsv;
#pragma unroll
      for (int j = 0; j < 4; ++j) wsv[j] = (short)f2bf(wv[j]);
      *(short4v*)(&WB[r][c4 * 4]) = wsv;
    }
    __syncthreads();

    const f32x4 vzero = {0.f, 0.f, 0.f, 0.f};
    f32x4 acc[4];
#pragma unroll
    for (int ct = 0; ct < 4; ++ct) acc[ct] = vzero;

    if (mode == 2) {
      // D[n][o]: A = X rows (wave's n-tile), B = W rows (o-tiles)
#pragma unroll
      for (int s = 0; s < 8; ++s) {
        short8 af = *(const short8*)(&XA[w * 16 + lr][s * 32 + g * 8]);
#pragma unroll
        for (int ct = 0; ct < 4; ++ct) {
          short8 bf = *(const short8*)(&WB[ct * 16 + lr][s * 32 + g * 8]);
          acc[ct] = MFMA16(af, bf, acc[ct], 0, 0, 0);
        }
      }
      // store: col(lr)=o, row(4g+r2)=n ; Vimg innermost = n&7 -> short4v
#pragma unroll
      for (int ct = 0; ct < 4; ++ct) {
        const int o = obi * 64 + ct * 16 + lr;
        const float bias = B[o];
        const int n0 = nb + w * 16 + g * 4;
        short4v vs;
#pragma unroll
        for (int r2 = 0; r2 < 4; ++r2) vs[r2] = (short)f2bf(acc[ct][r2] + bias);
        const size_t idx = (size_t)(n0 >> 5) * 8192 + (size_t)(o >> 5) * 1024
                         + (size_t)((n0 >> 4) & 1) * 512 + (size_t)((n0 >> 3) & 1) * 256
                         + (size_t)(o & 31) * 8 + (n0 & 7);
        *(short4v*)(Vimg + idx) = vs;
      }
    } else {
      // D[o][n]: A = W rows (wave's o-tile), B = X rows (n-tiles)
#pragma unroll
      for (int s = 0; s < 8; ++s) {
        short8 af = *(const short8*)(&WB[w * 16 + lr][s * 32 + g * 8]);
#pragma unroll
        for (int ct = 0; ct < 4; ++ct) {
          short8 bf = *(const short8*)(&XA[ct * 16 + lr][s * 32 + g * 8]);
          acc[ct] = MFMA16(af, bf, acc[ct], 0, 0, 0);
        }
      }
      // store: col(lr)=n, row(4g+r2)=o ; Qimg/Kimg innermost = o&7 -> short4v
      short* Out = (mode == 0) ? Qimg : Kimg;
      const float sc = (mode == 0) ? 0.0625f : 1.0f;
      const int o0 = obi * 64 + w * 16 + g * 4;   // 4 consecutive o per lane
      const float4v bv4 = *(const float4v*)(B + o0);
#pragma unroll
      for (int ct = 0; ct < 4; ++ct) {
        const int n = nb + ct * 16 + lr;
        short4v os;
#pragma unroll
        for (int r2 = 0; r2 < 4; ++r2) os[r2] = (short)f2bf((acc[ct][r2] + bv4[r2]) * sc);
        const size_t idx = (size_t)(n >> 5) * 8192 + (size_t)(o0 >> 4) * 512
                         + (size_t)((o0 >> 3) & 1) * 256 + (size_t)(n & 31) * 8 + (o0 & 7);
        *(short4v*)(Out + idx) = os;
      }
    }
  }
}

// ---------------------------------------------------------------------------
// flash: 256 threads = 4 waves, each wave owns 32 q rows (block = 128 q).
// grid 512 (SPLIT=8) -> 2 blocks/CU: independently-barriered blocks
// phase-skew so one block's MFMA covers the other's softmax VALU.
// Swapped QK^T (S^T = K@Q^T, 32x32): q lane-local; P packed in-register
// (cvt_pk + shfl_xor 32). exp/pack split in halves, each half's PV MFMAs
// issued before the other half's exp (intra-wave MFMA||VALU overlap).
// ---------------------------------------------------------------------------
template<int SPLIT>
__global__ __launch_bounds__(256, 2) void flash_kernel(
    const short* __restrict__ Qimg, const short* __restrict__ Kimg, const short* __restrict__ Vimg,
    float* __restrict__ Op, float2* __restrict__ Ml)
{
  constexpr int kIters = (kN / SPLIT) / kKVB;
  const int linear = (int)blockIdx.x;
  int sp, qb;
  if (SPLIT == 8) { sp = linear & 7; qb = linear >> 3; }                      // qb 0..63
  else { const int xcd = linear & 7; sp = xcd >> 1; qb = ((linear >> 3) << 1) | (xcd & 1); }
  const int kvblk0 = sp * (kN / SPLIT / 32);

  __shared__ short sbuf[2][2][8192];  // [dbuf][K/V][16KB tile] = 64 KB

  const int t = threadIdx.x;
  const int w = t >> 6, l = t & 63;
  const int hf = l >> 5;          // lane half
  const int lc = l & 31;          // lane col

  // prologue: stage iter 0 into buf 0 (4 KB per gll16 pass across block)
  {
    const short* kg = Kimg + (size_t)kvblk0 * 8192 + t * 8;
    const short* vg = Vimg + (size_t)kvblk0 * 8192 + t * 8;
#pragma unroll
    for (int p = 0; p < 4; ++p) {
      gll16(kg + p * 2048, &sbuf[0][0][p * 2048 + t * 8]);
      gll16(vg + p * 2048, &sbuf[0][1][p * 2048 + t * 8]);
    }
  }

  // Q fragments: 16 ksteps x short8 (64 VGPR)
  short8 qf[16];
  {
    const short* qsrc = Qimg + (size_t)(qb * 4 + w) * 8192 + l * 8;
#pragma unroll
    for (int ks = 0; ks < 16; ++ks) qf[ks] = *(const short8*)(qsrc + ks * 512);
  }

  f32x16 oacc[8];
#pragma unroll
  for (int dvt = 0; dvt < 8; ++dvt)
#pragma unroll
    for (int r = 0; r < 16; ++r) oacc[dvt][r] = 0.f;
  float mr = -1e30f, lsum = 0.f;

  asm volatile("s_waitcnt vmcnt(0)" ::: "memory");
  __syncthreads();

  for (int it = 0; it < kIters; ++it) {
    const int cur = it & 1;
    // prefetch next tile (issue early; lands under this iter's compute)
    if (it + 1 < kIters) {
      const short* kg = Kimg + (size_t)(kvblk0 + it + 1) * 8192 + t * 8;
      const short* vg = Vimg + (size_t)(kvblk0 + it + 1) * 8192 + t * 8;
      short* kb = &sbuf[cur ^ 1][0][0];
      short* vb = &sbuf[cur ^ 1][1][0];
#pragma unroll
      for (int p = 0; p < 4; ++p) {
        gll16(kg + p * 2048, kb + p * 2048 + t * 8);
        gll16(vg + p * 2048, vb + p * 2048 + t * 8);
      }
    }

    // ---- QK^T: S^T[32 kv][32 q], 16 ksteps ----
    f32x16 sacc;
#pragma unroll
    for (int r = 0; r < 16; ++r) sacc[r] = 0.f;
    __builtin_amdgcn_s_setprio(1);
#pragma unroll
    for (int ks = 0; ks < 16; ++ks) {
      short8 kf = *(const short8*)(&sbuf[cur][0][ks * 512 + l * 8]);
      sacc = MFMA32(kf, qf[ks], sacc, 0, 0, 0);
    }
    __builtin_amdgcn_s_setprio(0);

    // ---- online softmax (q = lane&31; lane holds 16 of 32 kv) ----
    float pmax = sacc[0];
#pragma unroll
    for (int r = 1; r < 16; ++r) pmax = fmaxf(pmax, sacc[r]);
    pmax = fmaxf(pmax, __shfl_xor(pmax, 32));
    if (!__all(pmax - mr <= 8.f)) {   // T13 defer-max (rare path)
      const float newm = fmaxf(mr, pmax);
      const float corr = __expf(mr - newm);  // first iter: 0
      mr = newm;
      lsum *= corr;
      // O rows are q' = (r&3)+8*(r>>2)+4*hf; corr for q' lives in lane q'
#pragma unroll
      for (int r = 0; r < 16; ++r) {
        const float c = __shfl(corr, (r & 3) + 8 * (r >> 2) + 4 * hf);
#pragma unroll
        for (int dvt = 0; dvt < 8; ++dvt) oacc[dvt][r] *= c;
      }
    }

    float psum = 0.f;
    // ---- half 0: exp r0..7, pack pa0, then its 8 PV MFMAs ----
#pragma unroll
    for (int r = 0; r < 8; ++r) { sacc[r] = __expf(sacc[r] - mr); psum += sacc[r]; }
    short8 pa0;
    {
      const unsigned A0 = cvtpk_bf16(sacc[0], sacc[1]);
      const unsigned A1 = cvtpk_bf16(sacc[2], sacc[3]);
      const unsigned B0 = cvtpk_bf16(sacc[4], sacc[5]);
      const unsigned B1 = cvtpk_bf16(sacc[6], sacc[7]);
      const unsigned sA0 = (unsigned)__shfl_xor((int)A0, 32);
      const unsigned sA1 = (unsigned)__shfl_xor((int)A1, 32);
      const unsigned sB0 = (unsigned)__shfl_xor((int)B0, 32);
      const unsigned sB1 = (unsigned)__shfl_xor((int)B1, 32);
      union { unsigned u[4]; short8 s; } pu;
      pu.u[0] = hf ? sB0 : A0;
      pu.u[1] = hf ? sB1 : A1;
      pu.u[2] = hf ? B0 : sA0;
      pu.u[3] = hf ? B1 : sA1;
      pa0 = pu.s;
    }
    __builtin_amdgcn_s_setprio(1);
#pragma unroll
    for (int dvt = 0; dvt < 8; ++dvt) {
      short8 vf = *(const short8*)(&sbuf[cur][1][(dvt * 2) * 512 + l * 8]);
      oacc[dvt] = MFMA32(pa0, vf, oacc[dvt], 0, 0, 0);
    }
    __builtin_amdgcn_s_setprio(0);

    // ---- half 1: exp r8..15 (overlaps half-0 MFMAs), pack pa1, PV ----
#pragma unroll
    for (int r = 8; r < 16; ++r) { sacc[r] = __expf(sacc[r] - mr); psum += sacc[r]; }
    short8 pa1;
    {
      const unsigned A0 = cvtpk_bf16(sacc[8], sacc[9]);
      const unsigned A1 = cvtpk_bf16(sacc[10], sacc[11]);
      const unsigned B0 = cvtpk_bf16(sacc[12], sacc[13]);
      const unsigned B1 = cvtpk_bf16(sacc[14], sacc[15]);
      const unsigned sA0 = (unsigned)__shfl_xor((int)A0, 32);
      const unsigned sA1 = (unsigned)__shfl_xor((int)A1, 32);
      const unsigned sB0 = (unsigned)__shfl_xor((int)B0, 32);
      const unsigned sB1 = (unsigned)__shfl_xor((int)B1, 32);
      union { unsigned u[4]; short8 s; } pu;
      pu.u[0] = hf ? sB0 : A0;
      pu.u[1] = hf ? sB1 : A1;
      pu.u[2] = hf ? B0 : sA0;
      pu.u[3] = hf ? B1 : sA1;
      pa1 = pu.s;
    }
    __builtin_amdgcn_s_setprio(1);
#pragma unroll
    for (int dvt = 0; dvt < 8; ++dvt) {
      short8 vf = *(const short8*)(&sbuf[cur][1][(dvt * 2 + 1) * 512 + l * 8]);
      oacc[dvt] = MFMA32(pa1, vf, oacc[dvt], 0, 0, 0);
    }
    __builtin_amdgcn_s_setprio(0);

    psum += __shfl_xor(psum, 32);
    lsum += psum;

    asm volatile("s_waitcnt vmcnt(0)" ::: "memory");  // prefetch landed
    __syncthreads();
  }

  // ---- per-split partials ----
  const int qrow0 = qb * 128 + w * 32;
#pragma unroll
  for (int dvt = 0; dvt < 8; ++dvt)
#pragma unroll
    for (int r = 0; r < 16; ++r) {
      const int q = qrow0 + (r & 3) + 8 * (r >> 2) + 4 * hf;
      Op[((size_t)sp * kN + q) * kD + dvt * 32 + lc] = oacc[dvt][r];
    }
  if (l < 32) Ml[(size_t)sp * kN + qrow0 + l] = make_float2(mr, lsum);
}

// ---------------------------------------------------------------------------
// merge: combine SPLIT partials per q row and normalize. grid 8192, block 256.
// ---------------------------------------------------------------------------
template<int SPLIT>
__global__ __launch_bounds__(256) void merge_kernel(
    const float* __restrict__ Op, const float2* __restrict__ Ml, float* __restrict__ out)
{
  const int qrow = blockIdx.x;
  const int d = threadIdx.x;
  float m[SPLIT], li[SPLIT];
  float M = -1e30f;
#pragma unroll
  for (int s = 0; s < SPLIT; ++s) {
    const float2 a = Ml[(size_t)s * kN + qrow];
    m[s] = a.x; li[s] = a.y;
    M = fmaxf(M, m[s]);
  }
  float L = 0.f, accv = 0.f;
#pragma unroll
  for (int s = 0; s < SPLIT; ++s) {
    const float wgt = __expf(m[s] - M);
    L += wgt * li[s];
    accv += wgt * Op[((size_t)s * kN + qrow) * kD + d];
  }
  out[(size_t)qrow * kD + d] = accv / L;
}

// ---------------------------------------------------------------------------
extern "C" void kernel_launch(void* const* d_in, const int* in_sizes, int n_in,
                              void* d_out, int out_size, void* d_ws, size_t ws_size,
                              hipStream_t stream)
{
  const float* q  = (const float*)d_in[0];
  const float* k  = (const float*)d_in[1];
  const float* v  = (const float*)d_in[2];
  const float* Wq = (const float*)d_in[3];
  const float* bq = (const float*)d_in[4];
  const float* Wk = (const float*)d_in[5];
  const float* bk = (const float*)d_in[6];
  const float* Wv = (const float*)d_in[7];
  const float* bv = (const float*)d_in[8];

  char* ws = (char*)d_ws;
  short* Qimg = (short*)(ws);
  short* Kimg = (short*)(ws + ((size_t)4 << 20));
  short* Vimg = (short*)(ws + ((size_t)8 << 20));
  const size_t opOff = (size_t)12 << 20;
  float* Op = (float*)(ws + opOff);

  proj_kernel<<<dim3(kN / 64, 3), 256, 0, stream>>>(
      q, k, v, Wq, bq, Wk, bk, Wv, bv, Qimg, Kimg, Vimg);

  const size_t opBytes8 = (size_t)8 * kN * kD * 4;
  const size_t need8 = opOff + opBytes8 + (size_t)8 * kN * 8;
  if (ws_size >= need8) {
    float2* Ml = (float2*)(ws + opOff + opBytes8);
    flash_kernel<8><<<dim3(512), 256, 0, stream>>>(Qimg, Kimg, Vimg, Op, Ml);
    merge_kernel<8><<<dim3(kN), 256, 0, stream>>>(Op, Ml, (float*)d_out);
  } else {
    const size_t opBytes4 = (size_t)4 * kN * kD * 4;
    float2* Ml = (float2*)(ws + opOff + opBytes4);
    flash_kernel<4><<<dim3(256), 256, 0, stream>>>(Qimg, Kimg, Vimg, Op, Ml);
    merge_kernel<4><<<dim3(kN), 256, 0, stream>>>(Op, Ml, (float*)d_out);
  }
}

// Round 5
// 100.326 us; speedup vs baseline: 1.1460x; 1.1460x over previous
//
#include <hip/hip_runtime.h>
#include <hip/hip_bf16.h>

// AttentionHead: out = softmax((q@Wq^T+bq) @ (k@Wk^T+bk)^T / 16) @ (v@Wv^T+bv)
// N=8192, DK=DV=256. f32 in/out, bf16 32x32x16 MFMA internally.
//
// ws layout:
//   [0,4M)    Qimg bf16 — Q in QK B-fragment image order (pre-scaled 1/16)
//   [4M,8M)   Kimg bf16 — K in QK A-fragment image order
//   [8M,12M)  Vimg bf16 — V in PV B-fragment image order
//   [12M,44M) Ops int16 [SPLIT][8192][256] — per-split O/l scaled by 4096
//   [44M,..)  Ml  float2 [SPLIT][8192]     — per-split (m, l)
//
// Image layouts (per 32-row kv/q block = 8192 shorts = 16 KB):
//   Kimg/Qimg: idx(r,k) = (r>>5)*8192 + (k>>4)*512 + ((k>>3)&1)*256 + (r&31)*8 + (k&7)
//   Vimg:      idx(kv,dv)= (kv>>5)*8192 + (dv>>5)*1024 + ((kv>>4)&1)*512
//                          + ((kv>>3)&1)*256 + (dv&31)*8 + (kv&7)
// These make LDS staging (global_load_lds) and all ds_read_b128 lane-linear.

typedef __attribute__((ext_vector_type(8))) short short8;
typedef __attribute__((ext_vector_type(4))) short short4v;
typedef __attribute__((ext_vector_type(4))) float f32x4;
typedef __attribute__((ext_vector_type(4))) float float4v;
typedef __attribute__((ext_vector_type(16))) float f32x16;

#define MFMA16 __builtin_amdgcn_mfma_f32_16x16x32_bf16
#define MFMA32 __builtin_amdgcn_mfma_f32_32x32x16_bf16

namespace {
constexpr int kN = 8192;
constexpr int kD = 256;
constexpr int kKVB = 32;   // kv rows per flash iteration
}

__device__ __forceinline__ unsigned short f2bf(float x) {
  union { float f; unsigned u; } v; v.f = x;
  unsigned r = v.u + 0x7FFFu + ((v.u >> 16) & 1u);  // RNE
  return (unsigned short)(r >> 16);
}

__device__ __forceinline__ unsigned cvtpk_bf16(float lo, float hi) {
  unsigned d;
  asm("v_cvt_pk_bf16_f32 %0, %1, %2" : "=v"(d) : "v"(lo), "v"(hi));
  return d;
}

// permlane32_swap: a' = [a_lo || b_lo], b' = [a_hi || b_hi]  (pure VALU)
__device__ __forceinline__ void plswap(unsigned& a, unsigned& b) {
  auto r = __builtin_amdgcn_permlane32_swap(a, b, false, false);
  a = r[0]; b = r[1];
}
__device__ __forceinline__ float xhalf_sum(float x) {
  unsigned u = __builtin_bit_cast(unsigned, x), v = u;
  plswap(u, v);
  return __builtin_bit_cast(float, u) + __builtin_bit_cast(float, v);
}
__device__ __forceinline__ float xhalf_max(float x) {
  unsigned u = __builtin_bit_cast(unsigned, x), v = u;
  plswap(u, v);
  return fmaxf(__builtin_bit_cast(float, u), __builtin_bit_cast(float, v));
}

__device__ __forceinline__ void gll16(const short* g, short* lp) {
  __builtin_amdgcn_global_load_lds(
      (const __attribute__((address_space(1))) void*)g,
      (__attribute__((address_space(3))) void*)lp, 16, 0, 0);
}

// ---------------------------------------------------------------------------
// proj: Y = X @ W^T + b -> fragment-image layouts.
// grid (128, 3): block owns a 64-row n-strip (X staged ONCE), loops 4 ob
// chunks of 64 o. Modes 0/1 use swapped operands (D rows = o) so image
// stores are coalesced short4v; mode 2 keeps D rows = n (Vimg short4v).
// ---------------------------------------------------------------------------
__global__ __launch_bounds__(256, 2) void proj_kernel(
    const float* __restrict__ qx, const float* __restrict__ kx, const float* __restrict__ vx,
    const float* __restrict__ Wq, const float* __restrict__ bq,
    const float* __restrict__ Wk, const float* __restrict__ bk,
    const float* __restrict__ Wv, const float* __restrict__ bv,
    short* __restrict__ Qimg, short* __restrict__ Kimg, short* __restrict__ Vimg)
{
  const int mode = blockIdx.y;
  const float* X; const float* W; const float* B;
  if (mode == 0)      { X = qx; W = Wq; B = bq; }
  else if (mode == 1) { X = kx; W = Wk; B = bk; }
  else                { X = vx; W = Wv; B = bv; }

  const int nb = blockIdx.x * 64;

  __shared__ short XA[64][264];
  __shared__ short WB[64][264];

  const int t  = threadIdx.x;
  const int c4 = t & 63;       // float4 column
  const int r0 = t >> 6;       // 4 rows/pass

  // stage X strip once (f32 -> bf16)
#pragma unroll
  for (int p = 0; p < 16; ++p) {
    const int r = p * 4 + r0;
    float4v xv = *(const float4v*)(X + (size_t)(nb + r) * kD + c4 * 4);
    short4v xs;
#pragma unroll
    for (int j = 0; j < 4; ++j) xs[j] = (short)f2bf(xv[j]);
    *(short4v*)(&XA[r][c4 * 4]) = xs;
  }

  const int w  = t >> 6;
  const int l  = t & 63;
  const int lr = l & 15;
  const int g  = l >> 4;

  for (int obi = 0; obi < 4; ++obi) {
    __syncthreads();   // protect WB from previous chunk's readers (covers XA 1st time)
#pragma unroll
    for (int p = 0; p < 16; ++p) {
      const int r = p * 4 + r0;
      float4v wv = *(const float4v*)(W + (size_t)(obi * 64 + r) * kD + c4 * 4);
      short4v wsv;
#pragma unroll
      for (int j = 0; j < 4; ++j) wsv[j] = (short)f2bf(wv[j]);
      *(short4v*)(&WB[r][c4 * 4]) = wsv;
    }
    __syncthreads();

    const f32x4 vzero = {0.f, 0.f, 0.f, 0.f};
    f32x4 acc[4];
#pragma unroll
    for (int ct = 0; ct < 4; ++ct) acc[ct] = vzero;

    if (mode == 2) {
      // D[n][o]: A = X rows (wave's n-tile), B = W rows (o-tiles)
#pragma unroll
      for (int s = 0; s < 8; ++s) {
        short8 af = *(const short8*)(&XA[w * 16 + lr][s * 32 + g * 8]);
#pragma unroll
        for (int ct = 0; ct < 4; ++ct) {
          short8 bf = *(const short8*)(&WB[ct * 16 + lr][s * 32 + g * 8]);
          acc[ct] = MFMA16(af, bf, acc[ct], 0, 0, 0);
        }
      }
      // store: col(lr)=o, row(4g+r2)=n ; Vimg innermost = n&7 -> short4v
#pragma unroll
      for (int ct = 0; ct < 4; ++ct) {
        const int o = obi * 64 + ct * 16 + lr;
        const float bias = B[o];
        const int n0 = nb + w * 16 + g * 4;
        short4v vs;
#pragma unroll
        for (int r2 = 0; r2 < 4; ++r2) vs[r2] = (short)f2bf(acc[ct][r2] + bias);
        const size_t idx = (size_t)(n0 >> 5) * 8192 + (size_t)(o >> 5) * 1024
                         + (size_t)((n0 >> 4) & 1) * 512 + (size_t)((n0 >> 3) & 1) * 256
                         + (size_t)(o & 31) * 8 + (n0 & 7);
        *(short4v*)(Vimg + idx) = vs;
      }
    } else {
      // D[o][n]: A = W rows (wave's o-tile), B = X rows (n-tiles)
#pragma unroll
      for (int s = 0; s < 8; ++s) {
        short8 af = *(const short8*)(&WB[w * 16 + lr][s * 32 + g * 8]);
#pragma unroll
        for (int ct = 0; ct < 4; ++ct) {
          short8 bf = *(const short8*)(&XA[ct * 16 + lr][s * 32 + g * 8]);
          acc[ct] = MFMA16(af, bf, acc[ct], 0, 0, 0);
        }
      }
      // store: col(lr)=n, row(4g+r2)=o ; Qimg/Kimg innermost = o&7 -> short4v
      short* Out = (mode == 0) ? Qimg : Kimg;
      const float sc = (mode == 0) ? 0.0625f : 1.0f;
      const int o0 = obi * 64 + w * 16 + g * 4;   // 4 consecutive o per lane
      const float4v bv4 = *(const float4v*)(B + o0);
#pragma unroll
      for (int ct = 0; ct < 4; ++ct) {
        const int n = nb + ct * 16 + lr;
        short4v os;
#pragma unroll
        for (int r2 = 0; r2 < 4; ++r2) os[r2] = (short)f2bf((acc[ct][r2] + bv4[r2]) * sc);
        const size_t idx = (size_t)(n >> 5) * 8192 + (size_t)(o0 >> 4) * 512
                         + (size_t)((o0 >> 3) & 1) * 256 + (size_t)(n & 31) * 8 + (o0 & 7);
        *(short4v*)(Out + idx) = os;
      }
    }
  }
}

// ---------------------------------------------------------------------------
// flash: 512 threads = 8 waves, each wave owns 32 q rows (block = 256 q).
// Swapped QK^T (S^T = K@Q^T, 32x32): q lane-local (q = lane&31).
// P packed fully in-register: cvt_pk + permlane32_swap (VALU only, no DS).
// exp/pack split in halves; each half's 8 PV MFMAs cover the other half's exp.
// K/V double-buffered in LDS via global_load_lds. grid = 32*SPLIT, 1 block/CU.
// Epilogue writes O/l as int16 x4096 (merge traffic halved).
// ---------------------------------------------------------------------------
template<int SPLIT>
__global__ __launch_bounds__(512) void flash_kernel(
    const short* __restrict__ Qimg, const short* __restrict__ Kimg, const short* __restrict__ Vimg,
    short* __restrict__ Ops, float2* __restrict__ Ml)
{
  constexpr int kIters = (kN / SPLIT) / kKVB;
  const int linear = (int)blockIdx.x;
  int sp, qb;
  if (SPLIT == 8) { sp = linear & 7; qb = linear >> 3; }                      // qb 0..31
  else { const int xcd = linear & 7; sp = xcd >> 1; qb = ((linear >> 3) << 1) | (xcd & 1); }
  const int kvblk0 = sp * (kN / SPLIT / 32);

  __shared__ short sbuf[2][2][8192];  // [dbuf][K/V][16KB tile] = 64 KB

  const int t = threadIdx.x;
  const int w = t >> 6, l = t & 63;
  const int hf = l >> 5;          // lane half
  const int lc = l & 31;          // lane col

  // prologue: stage iter 0 into buf 0
  {
    const short* kg = Kimg + (size_t)kvblk0 * 8192 + w * 512 + l * 8;
    const short* vg = Vimg + (size_t)kvblk0 * 8192 + w * 512 + l * 8;
    gll16(kg,        &sbuf[0][0][w * 512]);
    gll16(kg + 4096, &sbuf[0][0][4096 + w * 512]);
    gll16(vg,        &sbuf[0][1][w * 512]);
    gll16(vg + 4096, &sbuf[0][1][4096 + w * 512]);
  }

  // Q fragments: 16 ksteps x short8 (64 VGPR)
  short8 qf[16];
  {
    const short* qsrc = Qimg + (size_t)(qb * 8 + w) * 8192 + l * 8;
#pragma unroll
    for (int ks = 0; ks < 16; ++ks) qf[ks] = *(const short8*)(qsrc + ks * 512);
  }

  f32x16 oacc[8];
#pragma unroll
  for (int dvt = 0; dvt < 8; ++dvt)
#pragma unroll
    for (int r = 0; r < 16; ++r) oacc[dvt][r] = 0.f;
  float mr = -1e30f, lsum = 0.f;

  asm volatile("s_waitcnt vmcnt(0)" ::: "memory");
  __syncthreads();

  for (int it = 0; it < kIters; ++it) {
    const int cur = it & 1;
    // prefetch next tile (issue early; lands under this iter's compute)
    if (it + 1 < kIters) {
      const short* kg = Kimg + (size_t)(kvblk0 + it + 1) * 8192 + w * 512 + l * 8;
      const short* vg = Vimg + (size_t)(kvblk0 + it + 1) * 8192 + w * 512 + l * 8;
      short* kb = &sbuf[cur ^ 1][0][0];
      short* vb = &sbuf[cur ^ 1][1][0];
      gll16(kg,        kb + w * 512);
      gll16(kg + 4096, kb + 4096 + w * 512);
      gll16(vg,        vb + w * 512);
      gll16(vg + 4096, vb + 4096 + w * 512);
    }

    // ---- QK^T: S^T[32 kv][32 q], 16 ksteps ----
    f32x16 sacc;
#pragma unroll
    for (int r = 0; r < 16; ++r) sacc[r] = 0.f;
    __builtin_amdgcn_s_setprio(1);
#pragma unroll
    for (int ks = 0; ks < 16; ++ks) {
      short8 kf = *(const short8*)(&sbuf[cur][0][ks * 512 + l * 8]);
      sacc = MFMA32(kf, qf[ks], sacc, 0, 0, 0);
    }
    __builtin_amdgcn_s_setprio(0);

    // ---- online softmax (q = lane&31; lane holds 16 of 32 kv) ----
    float pmax = sacc[0];
#pragma unroll
    for (int r = 1; r < 16; ++r) pmax = fmaxf(pmax, sacc[r]);
    pmax = xhalf_max(pmax);
    if (!__all(pmax - mr <= 8.f)) {   // T13 defer-max (rare path)
      const float newm = fmaxf(mr, pmax);
      const float corr = __expf(mr - newm);  // first iter: 0
      mr = newm;
      lsum *= corr;
      // O rows are q' = (r&3)+8*(r>>2)+4*hf; corr for q' lives in lane q'
#pragma unroll
      for (int r = 0; r < 16; ++r) {
        const float c = __shfl(corr, (r & 3) + 8 * (r >> 2) + 4 * hf);
#pragma unroll
        for (int dvt = 0; dvt < 8; ++dvt) oacc[dvt][r] *= c;
      }
    }

    float psum = 0.f;
    // ---- half 0: exp r0..7, pack (cvt_pk + 2 permlane swaps), 8 PV MFMAs --
#pragma unroll
    for (int r = 0; r < 8; ++r) { sacc[r] = __expf(sacc[r] - mr); psum += sacc[r]; }
    short8 pa0;
    {
      unsigned A0 = cvtpk_bf16(sacc[0], sacc[1]);
      unsigned A1 = cvtpk_bf16(sacc[2], sacc[3]);
      unsigned B0 = cvtpk_bf16(sacc[4], sacc[5]);
      unsigned B1 = cvtpk_bf16(sacc[6], sacc[7]);
      plswap(A0, B0);   // A0 -> [A0_lo||B0_lo], B0 -> [A0_hi||B0_hi]
      plswap(A1, B1);
      union { unsigned u[4]; short8 s8; } pu;
      pu.u[0] = A0; pu.u[1] = A1; pu.u[2] = B0; pu.u[3] = B1;
      pa0 = pu.s8;
    }
    __builtin_amdgcn_s_setprio(1);
#pragma unroll
    for (int dvt = 0; dvt < 8; ++dvt) {
      short8 vf = *(const short8*)(&sbuf[cur][1][(dvt * 2) * 512 + l * 8]);
      oacc[dvt] = MFMA32(pa0, vf, oacc[dvt], 0, 0, 0);
    }
    __builtin_amdgcn_s_setprio(0);

    // ---- half 1: exp r8..15 (overlaps half-0 MFMAs), pack, 8 PV MFMAs ----
#pragma unroll
    for (int r = 8; r < 16; ++r) { sacc[r] = __expf(sacc[r] - mr); psum += sacc[r]; }
    short8 pa1;
    {
      unsigned A0 = cvtpk_bf16(sacc[8], sacc[9]);
      unsigned A1 = cvtpk_bf16(sacc[10], sacc[11]);
      unsigned B0 = cvtpk_bf16(sacc[12], sacc[13]);
      unsigned B1 = cvtpk_bf16(sacc[14], sacc[15]);
      plswap(A0, B0);
      plswap(A1, B1);
      union { unsigned u[4]; short8 s8; } pu;
      pu.u[0] = A0; pu.u[1] = A1; pu.u[2] = B0; pu.u[3] = B1;
      pa1 = pu.s8;
    }
    __builtin_amdgcn_s_setprio(1);
#pragma unroll
    for (int dvt = 0; dvt < 8; ++dvt) {
      short8 vf = *(const short8*)(&sbuf[cur][1][(dvt * 2 + 1) * 512 + l * 8]);
      oacc[dvt] = MFMA32(pa1, vf, oacc[dvt], 0, 0, 0);
    }
    __builtin_amdgcn_s_setprio(0);

    lsum += xhalf_sum(psum);

    asm volatile("s_waitcnt vmcnt(0)" ::: "memory");  // prefetch landed
    __syncthreads();
  }

  // ---- epilogue: write O/l scaled to int16 ----
  const float rl = 1.0f / lsum;        // uniform across the hf pair
  float cs[16];
#pragma unroll
  for (int r = 0; r < 16; ++r)
    cs[r] = __shfl(rl, (r & 3) + 8 * (r >> 2) + 4 * hf) * 4096.f;
  const int qrow0 = qb * 256 + w * 32;
#pragma unroll
  for (int dvt = 0; dvt < 8; ++dvt)
#pragma unroll
    for (int r = 0; r < 16; ++r) {
      const int q = qrow0 + (r & 3) + 8 * (r >> 2) + 4 * hf;
      float x = oacc[dvt][r] * cs[r];
      x = fminf(fmaxf(x, -32767.f), 32767.f);
      Ops[((size_t)sp * kN + q) * kD + dvt * 32 + lc] = (short)(int)rintf(x);
    }
  if (l < 32) Ml[(size_t)sp * kN + qrow0 + l] = make_float2(mr, lsum);
}

// ---------------------------------------------------------------------------
// merge: out[q] = sum_s exp(m_s-M)*l_s*(Ops_s/4096) / sum_s exp(m_s-M)*l_s
// grid kN/2, block 256: 2 q-rows per block, short2 per thread (coalesced).
// ---------------------------------------------------------------------------
template<int SPLIT>
__global__ __launch_bounds__(256) void merge_kernel(
    const short* __restrict__ Ops, const float2* __restrict__ Ml, float* __restrict__ out)
{
  const int t = threadIdx.x;
  const int qrow = blockIdx.x * 2 + (t >> 7);
  const int d0 = (t & 127) * 2;
  float m[SPLIT], li[SPLIT];
  float M = -1e30f;
#pragma unroll
  for (int s = 0; s < SPLIT; ++s) {
    const float2 a = Ml[(size_t)s * kN + qrow];
    m[s] = a.x; li[s] = a.y;
    M = fmaxf(M, m[s]);
  }
  float denom = 0.f, n0 = 0.f, n1 = 0.f;
#pragma unroll
  for (int s = 0; s < SPLIT; ++s) {
    const float wl = __expf(m[s] - M) * li[s];
    denom += wl;
    const unsigned u = *(const unsigned*)(Ops + ((size_t)s * kN + qrow) * kD + d0);
    n0 += wl * (float)(short)(u & 0xFFFFu);
    n1 += wl * (float)(short)(u >> 16);
  }
  const float inv = 1.0f / (denom * 4096.f);
  out[(size_t)qrow * kD + d0]     = n0 * inv;
  out[(size_t)qrow * kD + d0 + 1] = n1 * inv;
}

// ---------------------------------------------------------------------------
extern "C" void kernel_launch(void* const* d_in, const int* in_sizes, int n_in,
                              void* d_out, int out_size, void* d_ws, size_t ws_size,
                              hipStream_t stream)
{
  const float* q  = (const float*)d_in[0];
  const float* k  = (const float*)d_in[1];
  const float* v  = (const float*)d_in[2];
  const float* Wq = (const float*)d_in[3];
  const float* bq = (const float*)d_in[4];
  const float* Wk = (const float*)d_in[5];
  const float* bk = (const float*)d_in[6];
  const float* Wv = (const float*)d_in[7];
  const float* bv = (const float*)d_in[8];

  char* ws = (char*)d_ws;
  short* Qimg = (short*)(ws);
  short* Kimg = (short*)(ws + ((size_t)4 << 20));
  short* Vimg = (short*)(ws + ((size_t)8 << 20));
  const size_t opOff = (size_t)12 << 20;
  short* Ops = (short*)(ws + opOff);

  proj_kernel<<<dim3(kN / 64, 3), 256, 0, stream>>>(
      q, k, v, Wq, bq, Wk, bk, Wv, bv, Qimg, Kimg, Vimg);

  const size_t opBytes8 = (size_t)8 * kN * kD * 2;
  const size_t need8 = opOff + opBytes8 + (size_t)8 * kN * 8;
  if (ws_size >= need8) {
    float2* Ml = (float2*)(ws + opOff + opBytes8);
    flash_kernel<8><<<dim3(256), 512, 0, stream>>>(Qimg, Kimg, Vimg, Ops, Ml);
    merge_kernel<8><<<dim3(kN / 2), 256, 0, stream>>>(Ops, Ml, (float*)d_out);
  } else {
    const size_t opBytes4 = (size_t)4 * kN * kD * 2;
    float2* Ml = (float2*)(ws + opOff + opBytes4);
    flash_kernel<4><<<dim3(128), 512, 0, stream>>>(Qimg, Kimg, Vimg, Ops, Ml);
    merge_kernel<4><<<dim3(kN / 2), 256, 0, stream>>>(Ops, Ml, (float*)d_out);
  }
}